// Round 5
// baseline (708.534 us; speedup 1.0000x reference)
//
#include <hip/hip_runtime.h>
#include <math.h>

#define BB 512
#define TT 1024
#define LL 48
#define NW 4          // waves per block (per batch)
#define IW 12         // prev-tag range per wave

__device__ __forceinline__ float readlane_f(float v, int lane) {
    return __int_as_float(__builtin_amdgcn_readlane(__float_as_int(v), lane));
}

// Tournament argmax over s[0..47], first-max tie-break (used once, in epilogue).
__device__ __forceinline__ void argmax48(const float* s, float& bestv, int& besti) {
    float val[24];
    int   idx[24];
#pragma unroll
    for (int k = 0; k < 24; ++k) {
        bool c = s[2 * k + 1] > s[2 * k];
        val[k] = c ? s[2 * k + 1] : s[2 * k];
        idx[k] = c ? 2 * k + 1 : 2 * k;
    }
#pragma unroll
    for (int k = 0; k < 12; ++k) {
        bool c = val[2 * k + 1] > val[2 * k];
        val[k] = c ? val[2 * k + 1] : val[2 * k];
        idx[k] = c ? idx[2 * k + 1] : idx[2 * k];
    }
#pragma unroll
    for (int k = 0; k < 6; ++k) {
        bool c = val[2 * k + 1] > val[2 * k];
        val[k] = c ? val[2 * k + 1] : val[2 * k];
        idx[k] = c ? idx[2 * k + 1] : idx[2 * k];
    }
#pragma unroll
    for (int k = 0; k < 3; ++k) {
        bool c = val[2 * k + 1] > val[2 * k];
        val[k] = c ? val[2 * k + 1] : val[2 * k];
        idx[k] = c ? idx[2 * k + 1] : idx[2 * k];
    }
    bool c01 = val[1] > val[0];
    float bv = c01 ? val[1] : val[0];
    int   bi = c01 ? idx[1] : idx[0];
    bool c2 = val[2] > bv;
    bestv = c2 ? val[2] : bv;
    besti = c2 ? idx[2] : bi;
}

__global__ __launch_bounds__(256) void viterbi_kernel(
    const float* __restrict__ emissions,   // [B,T,L]
    const float* __restrict__ transitions, // [L,L]
    const float* __restrict__ start_tr,    // [L]
    const float* __restrict__ end_tr,      // [L]
    int* __restrict__ out)                 // [B,T] int32
{
    __shared__ unsigned char bp[(TT - 1) * LL];          // 49,104 B backpointers
    __shared__ unsigned long long cb[2][NW * LL];        // combine dbuf: 3,072 B

    const int b   = blockIdx.x;
    const int tid = threadIdx.x;
    const int w   = tid >> 6;              // wave id 0..3 (uniform per wave)
    const int j   = tid & 63;
    const int jc  = (j < LL) ? j : (LL - 1);  // lanes 48-63 mirror lane 47
    const int ibase = w * IW;

    // This wave's slice of transition columns: tc[k] = trans[ibase+k][jc]
    float tc[IW];
#pragma unroll
    for (int k = 0; k < IW; ++k)
        tc[k] = transitions[(ibase + k) * LL + jc];

    const float* em = emissions + (size_t)b * TT * LL;

    // v replicated in every wave: lane jc holds v[jc]
    float v = start_tr[jc] + em[jc];

    // 3-deep emission pipeline (two loads in flight)
    float e1 = em[1 * LL + jc];
    float e2 = em[2 * LL + jc];

#pragma unroll 3
    for (int t = 1; t < TT; ++t) {
        int tn = t + 2; if (tn >= TT) tn = TT - 1;
        float e3 = em[(size_t)tn * LL + jc];   // prefetch 2 iters ahead

        // partial scores for this wave's i-slice
        float s[IW];
#pragma unroll
        for (int k = 0; k < IW; ++k)
            s[k] = readlane_f(v, ibase + k) + tc[k];

        // argmax over 12, global indices, first-max tie-break
        float val[6]; int idx[6];
#pragma unroll
        for (int k = 0; k < 6; ++k) {
            bool c = s[2 * k + 1] > s[2 * k];
            val[k] = c ? s[2 * k + 1] : s[2 * k];
            idx[k] = ibase + (c ? 2 * k + 1 : 2 * k);
        }
#pragma unroll
        for (int k = 0; k < 3; ++k) {
            bool c = val[2 * k + 1] > val[2 * k];
            val[k] = c ? val[2 * k + 1] : val[2 * k];
            idx[k] = c ? idx[2 * k + 1] : idx[2 * k];
        }
        bool c01 = val[1] > val[0];
        float pv = c01 ? val[1] : val[0];
        int   pa = c01 ? idx[1] : idx[0];
        bool c2 = val[2] > pv;
        pv = c2 ? val[2] : pv;
        pa = c2 ? idx[2] : pa;

        // publish partial (val,idx) — contiguous b64, conflict-free
        const int p = t & 1;
        cb[p][w * LL + jc] =
            ((unsigned long long)(unsigned)pa << 32) | (unsigned)__float_as_uint(pv);

        __syncthreads();   // single barrier/step; double buffer makes it race-free

        // read all 4 partials (contiguous b64 per read), combine (lower w wins ties)
        float V0, V1, V2, V3; int A0, A1, A2, A3;
        {
            unsigned long long q0 = cb[p][0 * LL + jc];
            unsigned long long q1 = cb[p][1 * LL + jc];
            unsigned long long q2 = cb[p][2 * LL + jc];
            unsigned long long q3 = cb[p][3 * LL + jc];
            V0 = __uint_as_float((unsigned)q0); A0 = (int)(q0 >> 32);
            V1 = __uint_as_float((unsigned)q1); A1 = (int)(q1 >> 32);
            V2 = __uint_as_float((unsigned)q2); A2 = (int)(q2 >> 32);
            V3 = __uint_as_float((unsigned)q3); A3 = (int)(q3 >> 32);
        }
        bool ca = V1 > V0;  float va = ca ? V1 : V0;  int aa = ca ? A1 : A0;
        bool cbb = V3 > V2; float vb = cbb ? V3 : V2; int ab = cbb ? A3 : A2;
        bool cf = vb > va;
        float best = cf ? vb : va;
        int   arg  = cf ? ab : aa;

        v = best + e1;                          // identical in all 4 waves
        if (w == 0)                             // wave-uniform branch
            bp[(t - 1) * LL + jc] = (unsigned char)arg;

        e1 = e2; e2 = e3;
    }

    if (w != 0) return;   // epilogue + backtrack on wave 0 only (no barriers below)

    v += end_tr[jc];

    float sf[LL];
#pragma unroll
    for (int i = 0; i < LL; ++i)
        sf[i] = readlane_f(v, i);

    float bestv; int tag;
    argmax48(sf, bestv, tag);   // tag wave-uniform

    int* ob = out + (size_t)b * TT;
    if (j == 0) ob[TT - 1] = tag;

    // Backtrack: bp written & read by this same wave -> lgkmcnt ordering suffices.
    for (int hi = TT - 2; hi >= 0; hi -= 32) {
        int lo = hi - 31; if (lo < 0) lo = 0;
        int n = hi - lo + 1;

        unsigned int row[32];
#pragma unroll
        for (int k = 0; k < 32; ++k)
            row[k] = (unsigned int)bp[(lo + k) * LL + jc];

        int outv = 0;
#pragma unroll
        for (int k = 31; k >= 0; --k) {
            if (k < n) {
                tag = __builtin_amdgcn_readlane((int)row[k], tag);
                outv = (j == k) ? tag : outv;   // tag is SGPR -> single v_cndmask
            }
        }
        if (j < n) ob[lo + j] = outv;
    }
}

extern "C" void kernel_launch(void* const* d_in, const int* in_sizes, int n_in,
                              void* d_out, int out_size, void* d_ws, size_t ws_size,
                              hipStream_t stream) {
    const float* emissions   = (const float*)d_in[0];
    // d_in[1] = mask — unused by the reference decode body
    const float* transitions = (const float*)d_in[2];
    const float* start_tr    = (const float*)d_in[3];
    const float* end_tr      = (const float*)d_in[4];
    int* out = (int*)d_out;

    viterbi_kernel<<<dim3(BB), dim3(256), 0, stream>>>(
        emissions, transitions, start_tr, end_tr, out);
}